// Round 6
// baseline (127.409 us; speedup 1.0000x reference)
//
#include <hip/hip_runtime.h>

#define NC 4
#define CS 512
#define NS 256
#define HD 512
#define H  256
#define GAMMA_F 12.0f
#define PHASE_SCALE 62.83185307179586477f   // pi / 0.05

#define KT 16        // k-steps per staging round
#define KSPLIT 8     // k-slices (32 k each)

// Round 6: occupancy fix. Round-5 kernel was latency-bound at 2 waves/SIMD
// (VALUBusy 53%, 2.4x above 15.4us issue floor). K-split 8 -> 1024 blocks
// = 4 blocks/CU = 4 waves/SIMD; launch_bounds(256,4) caps VGPR at 128.
// grid: 4 chunks * 8 kslices * 8 hTiles(64) * 4 tTiles(64) = 1024 blocks
__global__ __launch_bounds__(256, 4) void score_partial(
    const float* __restrict__ heads,     // 2048 x 512
    const float* __restrict__ relations, // 2048 x 256
    const float* __restrict__ tails,     // 1024 x 512
    float* __restrict__ part)            // 8 planes of [4][512][256]
{
    __shared__ float2 sh[64][KT + 1];   // rotated head (re,im), +1 pad
    __shared__ float2 st[64][KT + 1];   // tail (re,im), +1 pad

    int bid = blockIdx.x;
    int c    = bid >> 8;          // chunk
    int rem  = bid & 255;
    int ks   = rem >> 5;          // k-slice 0..7
    int rem2 = rem & 31;
    int hT   = rem2 >> 2;         // 0..7
    int tT   = rem2 & 3;          // 0..3

    int hBase = c * CS + hT * 64;     // global head row
    int tBase = c * NS + tT * 64;     // global tail row
    int kSlice = ks * 32;             // k range [kSlice, kSlice+32)

    int tid = threadIdx.x;
    int tx = tid & 15;            // tail micro index
    int ty = tid >> 4;            // head micro index

    // staging: 64 rows x 4 lanes x 4 k-elems (float4)
    int srow = tid >> 2;          // 0..63
    int sk   = (tid & 3) * 4;     // 0,4,8,12

    float acc[4][4];
    #pragma unroll
    for (int m = 0; m < 4; ++m)
        #pragma unroll
        for (int n = 0; n < 4; ++n) acc[m][n] = 0.f;

    for (int r = 0; r < 32 / KT; ++r) {
        int kBase = kSlice + r * KT;

        // ---- global loads into regs ----
        const float* hp = heads + (size_t)(hBase + srow) * HD + kBase + sk;
        float4 hre = *reinterpret_cast<const float4*>(hp);
        float4 him = *reinterpret_cast<const float4*>(hp + H);
        float4 rel = *reinterpret_cast<const float4*>(
            relations + (size_t)(hBase + srow) * H + kBase + sk);
        const float* tp = tails + (size_t)(tBase + srow) * HD + kBase + sk;
        float4 tre = *reinterpret_cast<const float4*>(tp);
        float4 tim = *reinterpret_cast<const float4*>(tp + H);

        __syncthreads();   // previous round's LDS reads complete

        // ---- rotate heads inline, stage interleaved (re,im) ----
        {
            float s, cc;
            __sincosf(rel.x * PHASE_SCALE, &s, &cc);
            sh[srow][sk + 0] = make_float2(hre.x * cc - him.x * s,
                                           hre.x * s + him.x * cc);
            __sincosf(rel.y * PHASE_SCALE, &s, &cc);
            sh[srow][sk + 1] = make_float2(hre.y * cc - him.y * s,
                                           hre.y * s + him.y * cc);
            __sincosf(rel.z * PHASE_SCALE, &s, &cc);
            sh[srow][sk + 2] = make_float2(hre.z * cc - him.z * s,
                                           hre.z * s + him.z * cc);
            __sincosf(rel.w * PHASE_SCALE, &s, &cc);
            sh[srow][sk + 3] = make_float2(hre.w * cc - him.w * s,
                                           hre.w * s + him.w * cc);
        }
        st[srow][sk + 0] = make_float2(tre.x, tim.x);
        st[srow][sk + 1] = make_float2(tre.y, tim.y);
        st[srow][sk + 2] = make_float2(tre.z, tim.z);
        st[srow][sk + 3] = make_float2(tre.w, tim.w);

        __syncthreads();   // staging visible

        #pragma unroll
        for (int kk = 0; kk < KT; ++kk) {
            float2 hv[4], tv[4];
            hv[0] = sh[ty     ][kk];
            hv[1] = sh[ty + 16][kk];
            hv[2] = sh[ty + 32][kk];
            hv[3] = sh[ty + 48][kk];
            tv[0] = st[tx     ][kk];
            tv[1] = st[tx + 16][kk];
            tv[2] = st[tx + 32][kk];
            tv[3] = st[tx + 48][kk];
            #pragma unroll
            for (int m = 0; m < 4; ++m) {
                #pragma unroll
                for (int n = 0; n < 4; ++n) {
                    float dr = hv[m].x - tv[n].x;
                    float di = hv[m].y - tv[n].y;
                    acc[m][n] += __builtin_amdgcn_sqrtf(dr * dr + di * di);
                }
            }
        }
    }

    // epilogue: plain stores of this k-slice's partial plane
    float* plane = part + (size_t)ks * (NC * CS * NS);
    size_t cbase = (size_t)c * CS * NS;
    #pragma unroll
    for (int m = 0; m < 4; ++m) {
        int i0 = hT * 64 + ty + 16 * m;
        #pragma unroll
        for (int n = 0; n < 4; ++n) {
            int j0 = tT * 64 + tx + 16 * n;
            plane[cbase + (size_t)i0 * NS + j0] = acc[m][n];
        }
    }
}

// out = GAMMA - sum of 8 planes; 131072 threads, one float4 each
__global__ __launch_bounds__(256) void reduce_kernel(
    const float* __restrict__ part, float* __restrict__ out)
{
    const int PLANE = NC * CS * NS;   // 524288
    int idx = (blockIdx.x * 256 + threadIdx.x) * 4;
    float sx = 0.f, sy = 0.f, sz = 0.f, sw = 0.f;
    #pragma unroll
    for (int p = 0; p < KSPLIT; ++p) {
        float4 v = *reinterpret_cast<const float4*>(part + (size_t)p * PLANE + idx);
        sx += v.x; sy += v.y; sz += v.z; sw += v.w;
    }
    float4 r;
    r.x = GAMMA_F - sx;
    r.y = GAMMA_F - sy;
    r.z = GAMMA_F - sz;
    r.w = GAMMA_F - sw;
    *reinterpret_cast<float4*>(out + idx) = r;
}

extern "C" void kernel_launch(void* const* d_in, const int* in_sizes, int n_in,
                              void* d_out, int out_size, void* d_ws, size_t ws_size,
                              hipStream_t stream) {
    (void)in_sizes; (void)n_in; (void)ws_size; (void)out_size;
    const float* heads = (const float*)d_in[0];
    const float* rels  = (const float*)d_in[1];
    const float* tails = (const float*)d_in[2];
    float* part = (float*)d_ws;   // 8 planes x 2 MB = 16 MB

    score_partial<<<1024, 256, 0, stream>>>(heads, rels, tails, part);
    reduce_kernel<<<512, 256, 0, stream>>>(part, (float*)d_out);
}

// Round 7
// 99.352 us; speedup vs baseline: 1.2824x; 1.2824x over previous
//
#include <hip/hip_runtime.h>

#define NC 4
#define CS 512
#define NS 256
#define HD 512
#define H  256
#define GAMMA_F 12.0f
#define PHASE_SCALE 62.83185307179586477f   // pi / 0.05

#define KT 16        // k-steps per staging round
#define KSPLIT 4     // k-slices (64 k each)
#define ROUNDS 4     // 64 / KT

// Round 7: revert to round-5 shape (KSPLIT=4, 512 blocks — round 6's 1024
// blocks destroyed L2 locality, FETCH 26->88MB). Add 1-round software
// pipeline: next round's global loads issue BEFORE current round's compute,
// hiding ~900cyc HBM latency behind ~4600cyc of VALU work.
// grid: 4 chunks * 4 kslices * 8 hTiles(64) * 4 tTiles(64) = 512 blocks
__global__ __launch_bounds__(256, 2) void score_partial(
    const float* __restrict__ heads,     // 2048 x 512
    const float* __restrict__ relations, // 2048 x 256
    const float* __restrict__ tails,     // 1024 x 512
    float* __restrict__ part)            // 4 planes of [4][512][256]
{
    __shared__ float2 sh[64][KT + 1];   // rotated head (re,im), +1 pad
    __shared__ float2 st[64][KT + 1];   // tail (re,im), +1 pad

    int bid = blockIdx.x;
    int c    = bid >> 7;          // chunk
    int rem  = bid & 127;
    int ks   = rem >> 5;          // k-slice 0..3
    int rem2 = rem & 31;
    int hT   = rem2 >> 2;         // 0..7
    int tT   = rem2 & 3;          // 0..3

    int hBase = c * CS + hT * 64;     // global head row
    int tBase = c * NS + tT * 64;     // global tail row
    int kSlice = ks * 64;             // k range [kSlice, kSlice+64)

    int tid = threadIdx.x;
    int tx = tid & 15;            // tail micro index
    int ty = tid >> 4;            // head micro index

    // staging: 64 rows x 4 lanes x 4 k-elems (float4)
    int srow = tid >> 2;          // 0..63
    int sk   = (tid & 3) * 4;     // 0,4,8,12

    const float* hrow = heads + (size_t)(hBase + srow) * HD + kSlice + sk;
    const float* rrow = relations + (size_t)(hBase + srow) * H + kSlice + sk;
    const float* trow = tails + (size_t)(tBase + srow) * HD + kSlice + sk;

    float acc[4][4];
    #pragma unroll
    for (int m = 0; m < 4; ++m)
        #pragma unroll
        for (int n = 0; n < 4; ++n) acc[m][n] = 0.f;

    // ---- prologue: load round 0 ----
    float4 hre = *reinterpret_cast<const float4*>(hrow);
    float4 him = *reinterpret_cast<const float4*>(hrow + H);
    float4 rel = *reinterpret_cast<const float4*>(rrow);
    float4 tre = *reinterpret_cast<const float4*>(trow);
    float4 tim = *reinterpret_cast<const float4*>(trow + H);

    for (int r = 0; r < ROUNDS; ++r) {
        __syncthreads();   // previous round's LDS reads complete

        // ---- rotate heads inline, stage interleaved (re,im) ----
        {
            float s, cc;
            __sincosf(rel.x * PHASE_SCALE, &s, &cc);
            sh[srow][sk + 0] = make_float2(hre.x * cc - him.x * s,
                                           hre.x * s + him.x * cc);
            __sincosf(rel.y * PHASE_SCALE, &s, &cc);
            sh[srow][sk + 1] = make_float2(hre.y * cc - him.y * s,
                                           hre.y * s + him.y * cc);
            __sincosf(rel.z * PHASE_SCALE, &s, &cc);
            sh[srow][sk + 2] = make_float2(hre.z * cc - him.z * s,
                                           hre.z * s + him.z * cc);
            __sincosf(rel.w * PHASE_SCALE, &s, &cc);
            sh[srow][sk + 3] = make_float2(hre.w * cc - him.w * s,
                                           hre.w * s + him.w * cc);
        }
        st[srow][sk + 0] = make_float2(tre.x, tim.x);
        st[srow][sk + 1] = make_float2(tre.y, tim.y);
        st[srow][sk + 2] = make_float2(tre.z, tim.z);
        st[srow][sk + 3] = make_float2(tre.w, tim.w);

        __syncthreads();   // staging visible

        // ---- issue NEXT round's loads; latency overlaps compute below ----
        if (r + 1 < ROUNDS) {
            int o = (r + 1) * KT;
            hre = *reinterpret_cast<const float4*>(hrow + o);
            him = *reinterpret_cast<const float4*>(hrow + o + H);
            rel = *reinterpret_cast<const float4*>(rrow + o);
            tre = *reinterpret_cast<const float4*>(trow + o);
            tim = *reinterpret_cast<const float4*>(trow + o + H);
        }

        #pragma unroll
        for (int kk = 0; kk < KT; ++kk) {
            float2 hv[4], tv[4];
            hv[0] = sh[ty     ][kk];
            hv[1] = sh[ty + 16][kk];
            hv[2] = sh[ty + 32][kk];
            hv[3] = sh[ty + 48][kk];
            tv[0] = st[tx     ][kk];
            tv[1] = st[tx + 16][kk];
            tv[2] = st[tx + 32][kk];
            tv[3] = st[tx + 48][kk];
            #pragma unroll
            for (int m = 0; m < 4; ++m) {
                #pragma unroll
                for (int n = 0; n < 4; ++n) {
                    float dr = hv[m].x - tv[n].x;
                    float di = hv[m].y - tv[n].y;
                    acc[m][n] += __builtin_amdgcn_sqrtf(dr * dr + di * di);
                }
            }
        }
    }

    // epilogue: plain stores of this k-slice's partial plane
    float* plane = part + (size_t)ks * (NC * CS * NS);
    size_t cbase = (size_t)c * CS * NS;
    #pragma unroll
    for (int m = 0; m < 4; ++m) {
        int i0 = hT * 64 + ty + 16 * m;
        #pragma unroll
        for (int n = 0; n < 4; ++n) {
            int j0 = tT * 64 + tx + 16 * n;
            plane[cbase + (size_t)i0 * NS + j0] = acc[m][n];
        }
    }
}

// out = GAMMA - sum of 4 planes; 131072 threads, one float4 each
__global__ __launch_bounds__(256) void reduce_kernel(
    const float* __restrict__ part, float* __restrict__ out)
{
    const int PLANE = NC * CS * NS;   // 524288
    int idx = (blockIdx.x * 256 + threadIdx.x) * 4;
    float sx = 0.f, sy = 0.f, sz = 0.f, sw = 0.f;
    #pragma unroll
    for (int p = 0; p < KSPLIT; ++p) {
        float4 v = *reinterpret_cast<const float4*>(part + (size_t)p * PLANE + idx);
        sx += v.x; sy += v.y; sz += v.z; sw += v.w;
    }
    float4 r;
    r.x = GAMMA_F - sx;
    r.y = GAMMA_F - sy;
    r.z = GAMMA_F - sz;
    r.w = GAMMA_F - sw;
    *reinterpret_cast<float4*>(out + idx) = r;
}

extern "C" void kernel_launch(void* const* d_in, const int* in_sizes, int n_in,
                              void* d_out, int out_size, void* d_ws, size_t ws_size,
                              hipStream_t stream) {
    (void)in_sizes; (void)n_in; (void)ws_size; (void)out_size;
    const float* heads = (const float*)d_in[0];
    const float* rels  = (const float*)d_in[1];
    const float* tails = (const float*)d_in[2];
    float* part = (float*)d_ws;   // 4 planes x 2 MB = 8 MB

    score_partial<<<512, 256, 0, stream>>>(heads, rels, tails, part);
    reduce_kernel<<<512, 256, 0, stream>>>(part, (float*)d_out);
}